// Round 11
// baseline (67.670 us; speedup 1.0000x reference)
//
#include <hip/hip_runtime.h>
#include <math.h>

// KDE as GEMM: sqd = ||x||^2 + ||t||^2 - 2 x.t ; exp2(EXP2_SCALE*sqd).
//
// R11 = R9's light hot loop + fused output (2 nodes, no reduce kernel):
//  - kde_prep: fp32->bf16 (RNE) test+train, scaled norms, AND zeroes out
//    (out is re-poisoned before every replay; prep rewrites it each call).
//  - kde_main: R9 structure: 512 blocks x 4 waves = 16 test-groups x 32
//    train-quarters; hot loop reads bf16 fragments straight off row-major
//    arrays (lane = point, 8 contiguous dims), 2 MFMA + 4 exp2 per tile;
//    xor-shuffle col-reduce; epilogue atomicAdds into out (32 adds/address).
//
// ws bytes: [0,4K) xnorm | [4K,20K) tnorm | [256K,384K) testB | [512K,1M) trainB

#define D          64
#define N_TRAIN    4096
#define N_TEST     1024
#define Q          32                      // train quarters
#define RPQ        (N_TRAIN / Q)           // 128 rows/quarter
#define TPQ        (RPQ / 16)              // 8 tiles/wave
#define EXP2_SCALE (-450.84220027780106f)  // -log2(e)/0.0032
#define NEG2SCALE  (901.6844005556021f)    // -2*EXP2_SCALE
#define COEF       (9.973557010035818f)    // 1/sqrt(2*pi*var)
#define MEAN_SCALE (COEF / 4096.0f)

typedef __attribute__((ext_vector_type(8))) __bf16 bf16x8;
typedef __attribute__((ext_vector_type(4))) float  f32x4;

__device__ __forceinline__ unsigned short f2bf(float f) {
    unsigned int u = __float_as_uint(f);
    return (unsigned short)((u + 0x7fffu + ((u >> 16) & 1u)) >> 16);  // RNE
}

__global__ __launch_bounds__(256) void kde_prep(
    const float* __restrict__ test,
    const float* __restrict__ train,
    float* __restrict__ xn, float* __restrict__ tn,
    unsigned short* __restrict__ testB,
    unsigned short* __restrict__ trainB,
    float* __restrict__ out)
{
    const int j = blockIdx.x * 256 + threadIdx.x;   // 0..81919

    // fp32 -> bf16, 4 elements per thread (coalesced both sides).
    {
        const bool isT = (j < 16384);               // 1024*64/4 test float4s
        const float4 v = isT ? ((const float4*)test)[j]
                             : ((const float4*)train)[j - 16384];
        ushort4 o;
        o.x = f2bf(v.x); o.y = f2bf(v.y); o.z = f2bf(v.z); o.w = f2bf(v.w);
        if (isT) ((ushort4*)testB)[j] = o;
        else     ((ushort4*)trainB)[j - 16384] = o;
    }

    if (j < N_TEST) out[j] = 0.0f;                  // out re-poisoned each call

    // Scaled squared norms from the fp32 originals.
    if (j < N_TEST + N_TRAIN) {
        const float* src = (j < N_TEST) ? (test + (size_t)j * D)
                                        : (train + (size_t)(j - N_TEST) * D);
        const float4* p = (const float4*)src;
        float n0 = 0.f, n1 = 0.f, n2 = 0.f, n3 = 0.f;
        #pragma unroll
        for (int c = 0; c < D / 4; ++c) {
            float4 v = p[c];
            n0 = fmaf(v.x, v.x, n0); n1 = fmaf(v.y, v.y, n1);
            n2 = fmaf(v.z, v.z, n2); n3 = fmaf(v.w, v.w, n3);
        }
        const float s = ((n0 + n1) + (n2 + n3)) * EXP2_SCALE;
        if (j < N_TEST) xn[j] = s; else tn[j - N_TEST] = s;
    }
}

__global__ __launch_bounds__(256) void kde_main(
    const unsigned short* __restrict__ testB,
    const unsigned short* __restrict__ trainB,
    const float* __restrict__ xn,
    const float* __restrict__ tn,
    float* __restrict__ out)
{
    const int lane = threadIdx.x & 63;
    const int wv   = threadIdx.x >> 6;
    const int q    = blockIdx.x & (Q - 1);
    const int ig   = blockIdx.x >> 5;          // 0..15
    const int i0   = (ig * 4 + wv) * 16;       // test-tile base
    const int r16  = lane & 15;                // A-row / B-col within tile
    const int quad = lane >> 4;                // k-group

    // A fragments: test rows i0+r16, dims quad*8..+7 and +32.
    const unsigned short* ta = testB + (size_t)(i0 + r16) * D + quad * 8;
    const bf16x8 a0 = *(const bf16x8*)ta;
    const bf16x8 a1 = *(const bf16x8*)(ta + 32);

    // Epilogue rows = quad*4+r: their scaled test norms.
    float xnr[4];
    #pragma unroll
    for (int r = 0; r < 4; ++r) xnr[r] = xn[i0 + quad * 4 + r];

    float sum[4] = {0.f, 0.f, 0.f, 0.f};
    const int n0base = q * RPQ;

    for (int tIdx = 0; tIdx < TPQ; ++tIdx) {
        const int n0 = n0base + tIdx * 16;
        const unsigned short* tb = trainB + (size_t)(n0 + r16) * D + quad * 8;
        const bf16x8 b0 = *(const bf16x8*)tb;
        const bf16x8 b1 = *(const bf16x8*)(tb + 32);
        f32x4 acc = {0.f, 0.f, 0.f, 0.f};
        acc = __builtin_amdgcn_mfma_f32_16x16x32_bf16(a0, b0, acc, 0, 0, 0);
        acc = __builtin_amdgcn_mfma_f32_16x16x32_bf16(a1, b1, acc, 0, 0, 0);
        // C/D: col = lane&15 (train n0+col), row = quad*4+reg (test).
        const float tnn = tn[n0 + r16];
        #pragma unroll
        for (int r = 0; r < 4; ++r)
            sum[r] += exp2f(fmaf(acc[r], NEG2SCALE, xnr[r] + tnn));
    }

    // Reduce over the 16 col-lanes (xor masks touch lane&15 bits only).
    #pragma unroll
    for (int m = 1; m <= 8; m <<= 1) {
        #pragma unroll
        for (int r = 0; r < 4; ++r) sum[r] += __shfl_xor(sum[r], m, 64);
    }

    if (r16 == 0) {   // lanes 0,16,32,48 hold rows quad*4..quad*4+3
        #pragma unroll
        for (int r = 0; r < 4; ++r)
            atomicAdd(&out[i0 + quad * 4 + r], sum[r] * MEAN_SCALE);
    }
}

extern "C" void kernel_launch(void* const* d_in, const int* in_sizes, int n_in,
                              void* d_out, int out_size, void* d_ws, size_t ws_size,
                              hipStream_t stream) {
    const float* test  = (const float*)d_in[0];   // [4,256,64]
    const float* train = (const float*)d_in[1];   // [4096,64]
    float* out = (float*)d_out;                   // 1024 floats
    char*  ws  = (char*)d_ws;

    float*          xnp    = (float*)(ws);                 // 4 KB
    float*          tnp    = (float*)(ws + 4096);          // 16 KB
    unsigned short* testB  = (unsigned short*)(ws + 262144);   // 128 KB
    unsigned short* trainB = (unsigned short*)(ws + 524288);   // 512 KB

    kde_prep<<<dim3(320), dim3(256), 0, stream>>>(test, train, xnp, tnp, testB, trainB, out);
    kde_main<<<dim3(512), dim3(256), 0, stream>>>(testB, trainB, xnp, tnp, out);
}